// Round 6
// baseline (303.534 us; speedup 1.0000x reference)
//
#include <hip/hip_runtime.h>
#include <math.h>

#define NB 256
#define NV 32000
#define ND 1024
#define NT 64

// ---- GEMM config ----
#define GN 64
#define BM 128             // rows per block (M-split x2)
#define ASTR 40            // row stride (f16): [h x16][q x16][pad x8]; 80 B -> all-8 bank phases
#define NKB 64             // 1024/16 k-blocks
#define AHALF 6144         // f16 per (kb, M-half) slab: 128*40=5120 padded to 6144 (12288 B, 12 gload_lds)
#define AKB (2 * AHALF)    // f16 per kb (both halves) = 12288 (24576 B)
#define INV2048F 4.8828125e-4f

// ---- sampling config ----
#define NBIN 1024
#define HSTR 1032                       // padded copy stride (u32) to decorrelate banks
#define HTOT (4 * HSTR)                 // lo0|lo1|hc0|hc1 = 4128 u32
#define FIX2 4294967296.0   // 2^32
#define SMASK ((1ull << 48) - 1ull)
#define SMEM_BYTES (NV * 4 + HTOT * 4)  // 128000 + 16512 = 144512 B

typedef _Float16 f16x8 __attribute__((ext_vector_type(8)));
typedef _Float16 f16x4 __attribute__((ext_vector_type(4)));
typedef float f32x16 __attribute__((ext_vector_type(16)));
typedef __attribute__((address_space(3))) void lds_void;
typedef __attribute__((address_space(1))) void glb_void;

struct RowP2 {
  unsigned long long basePack;
  unsigned long long toppZfix;
  unsigned pfx;
  int ktop;
  float invZ;
  unsigned ustar;
  int m;
  int cEq;
};

__device__ __forceinline__ unsigned mono_enc(float f) {
  unsigned u = __float_as_uint(f);
  return (u & 0x80000000u) ? ~u : (u | 0x80000000u);
}
__device__ __forceinline__ float mono_dec(unsigned u) {
  return (u & 0x80000000u) ? __uint_as_float(u & 0x7FFFFFFFu) : __uint_as_float(~u);
}

// ---------------- convert A: direct register conversion, halved-slab layout ----------
// g in [0,65536): kb = g>>10, r = (g>>2)&255, c = g&3; h = r>>7, rr = r&127.
// Slab: A3[kb*AKB + h*AHALF + rr*ASTR + {c*4 | 16+c*4}]
__global__ __launch_bounds__(256) void convert_A(const float* __restrict__ hidden,
                                                 _Float16* __restrict__ A3) {
  const int g = blockIdx.x * 256 + threadIdx.x;
  const int kb = g >> 10, rc = g & 1023, r = rc >> 2, c = rc & 3;
  const int h = r >> 7, rr = r & 127;
  const float4 a4 = *(const float4*)(hidden + (size_t)r * ND + kb * 16 + c * 4);
  const float v[4] = {a4.x, a4.y, a4.z, a4.w};
  f16x4 h4, q4;
#pragma unroll
  for (int q = 0; q < 4; q++) {
    const _Float16 hh = (_Float16)v[q];
    h4[q] = hh;
    q4[q] = (_Float16)((v[q] - (float)hh) * 2048.0f);
  }
  _Float16* base = A3 + (size_t)kb * AKB + h * AHALF + rr * ASTR;
  *(f16x4*)(base + c * 4) = h4;
  *(f16x4*)(base + 16 + c * 4) = q4;
}

// ---------------- MFMA f16-split GEMM, BM=128 M-split, 32-row wave strips ----------
// TLP attack: 1008 blocks x 4 waves = 16 waves/CU (4/SIMD, 2x R5). Per-wave tile 32x64:
// 6 ds_read_b128 : 6 MFMA per k-step. LDS 36.9 KB -> 4 blocks/CU.
// XCD pairing: bid -> {x=bid&7 (XCD), h=(bid>>3)&1, n=(bid>>4)*8+x} puts the two
// M-halves of an N-panel (bids b, b+8) on the SAME XCD concurrently -> emb re-read
// is an L2 hit (no HBM doubling from the M-split).
// VMEM queue/wave: entering iter k: [A_k(3), B_{k+1}(1)]; issue A_{k+1}(3), B_{k+2}(1)
//   -> vmcnt(5) drains A_k; vmcnt(4) drains B_{k+1}. Tail: 4/3/0.
__global__ __launch_bounds__(256, 4) void gemm_f16s(
    const float* __restrict__ Bm, const _Float16* __restrict__ A3,
    const float* __restrict__ temp, unsigned* __restrict__ rowmax,
    float* __restrict__ C) {
  __shared__ _Float16 Als[2][AHALF];      // 24,576 B
  __shared__ _Float16 Bls[2][GN * ASTR];  // 10,240 B
  __shared__ float s_invT[256];
  __shared__ unsigned s_pm[256];

  const int bid = blockIdx.x;
  const int x = bid & 7, h = (bid >> 3) & 1;
  const int n = (bid >> 4) * 8 + x;
  if (n >= NV / GN) return;  // 1008-block grid, 8 idle
  const int n0 = n * GN;

  const int t = threadIdx.x;
  const int l = t & 63, w = t >> 6;
  s_invT[t] = 1.0f / temp[t];
  s_pm[t] = 0u;

  f32x16 accH[2] = {};  // h*h'
  f32x16 accC[2] = {};  // h*q' + q*h' (scaled by 2048)

  const int bn = t >> 2, bk4 = (t & 3) * 4;
  const int l31 = l & 31, lh = l >> 5;
  const int ka = lh * 8;

  const float* browp = Bm + (size_t)(n0 + bn) * ND + bk4;
  const char* gaBase = (const char*)A3 + h * (AHALF * 2) + w * 3072 + l * 16;
  char* laB0 = (char*)&Als[0][0] + w * 3072;
  char* laB1 = (char*)&Als[1][0] + w * 3072;

#define ISSUE_A(kbn, LA)                                                        \
  do {                                                                          \
    const char* ga_ = gaBase + (size_t)(kbn) * (AKB * 2);                       \
    _Pragma("unroll") for (int i_ = 0; i_ < 3; i_++)                            \
        __builtin_amdgcn_global_load_lds((const glb_void*)(ga_ + i_ * 1024),    \
                                         (lds_void*)((LA) + i_ * 1024), 16, 0,  \
                                         0);                                    \
  } while (0)

#define BCONV(BV, DST)                                                          \
  do {                                                                          \
    f16x4 h4_, q4_;                                                             \
    const float vv_[4] = {(BV).x, (BV).y, (BV).z, (BV).w};                      \
    _Pragma("unroll") for (int j_ = 0; j_ < 4; j_++) {                          \
      const _Float16 h_ = (_Float16)vv_[j_];                                    \
      h4_[j_] = h_;                                                             \
      q4_[j_] = (_Float16)((vv_[j_] - (float)h_) * 2048.0f);                    \
    }                                                                           \
    _Float16* prow_ = (DST) + bn * ASTR;                                        \
    *(f16x4*)(prow_ + bk4) = h4_;                                               \
    *(f16x4*)(prow_ + 16 + bk4) = q4_;                                          \
  } while (0)

#define COMPUTE(CUR)                                                                     \
  do {                                                                                   \
    const _Float16* Ap_ = &Als[CUR][0] + (size_t)(w * 32 + l31) * ASTR + ka;             \
    const _Float16* Bp_ = &Bls[CUR][0] + (size_t)l31 * ASTR + ka;                        \
    f16x8 ah_ = *(const f16x8*)(Ap_);                                                    \
    f16x8 b0h_ = *(const f16x8*)(Bp_);                                                   \
    f16x8 b1h_ = *(const f16x8*)(Bp_ + 32 * ASTR);                                       \
    accH[0] = __builtin_amdgcn_mfma_f32_32x32x16_f16(ah_, b0h_, accH[0], 0, 0, 0);       \
    accH[1] = __builtin_amdgcn_mfma_f32_32x32x16_f16(ah_, b1h_, accH[1], 0, 0, 0);       \
    f16x8 b0q_ = *(const f16x8*)(Bp_ + 16);                                              \
    f16x8 b1q_ = *(const f16x8*)(Bp_ + 32 * ASTR + 16);                                  \
    accC[0] = __builtin_amdgcn_mfma_f32_32x32x16_f16(ah_, b0q_, accC[0], 0, 0, 0);       \
    accC[1] = __builtin_amdgcn_mfma_f32_32x32x16_f16(ah_, b1q_, accC[1], 0, 0, 0);       \
    f16x8 aq_ = *(const f16x8*)(Ap_ + 16);                                               \
    accC[0] = __builtin_amdgcn_mfma_f32_32x32x16_f16(aq_, b0h_, accC[0], 0, 0, 0);       \
    accC[1] = __builtin_amdgcn_mfma_f32_32x32x16_f16(aq_, b1h_, accC[1], 0, 0, 0);       \
  } while (0)

  // ---- prologue: stage tile 0 into buf0; leave B[1] in flight ----
  ISSUE_A(0, laB0);
  __builtin_amdgcn_sched_barrier(0);
  float4 bv0 = *(const float4*)(browp);
  __builtin_amdgcn_sched_barrier(0);
  float4 bvA = *(const float4*)(browp + 16);  // B[1]
  __builtin_amdgcn_sched_barrier(0);
  asm volatile("s_waitcnt vmcnt(1)" ::: "memory");  // A0(3)+B0 done; B1 in flight
  BCONV(bv0, &Bls[0][0]);
  asm volatile("s_waitcnt lgkmcnt(0)\ns_barrier" ::: "memory");

  float4 bvB;
  for (int kb = 0; kb < 62; kb += 2) {
    ISSUE_A(kb + 1, laB1);
    __builtin_amdgcn_sched_barrier(0);
    bvB = *(const float4*)(browp + (size_t)(kb + 2) * 16);
    __builtin_amdgcn_sched_barrier(0);
    asm volatile("s_waitcnt vmcnt(5)" ::: "memory");  // drain A_k
    COMPUTE(0);
    __builtin_amdgcn_sched_barrier(0);
    asm volatile("s_waitcnt vmcnt(4)" ::: "memory");  // drain B_{k+1}
    BCONV(bvA, &Bls[1][0]);
    asm volatile("s_waitcnt lgkmcnt(0)\ns_barrier" ::: "memory");

    ISSUE_A(kb + 2, laB0);
    __builtin_amdgcn_sched_barrier(0);
    bvA = *(const float4*)(browp + (size_t)(kb + 3) * 16);
    __builtin_amdgcn_sched_barrier(0);
    asm volatile("s_waitcnt vmcnt(5)" ::: "memory");
    COMPUTE(1);
    __builtin_amdgcn_sched_barrier(0);
    asm volatile("s_waitcnt vmcnt(4)" ::: "memory");
    BCONV(bvB, &Bls[0][0]);
    asm volatile("s_waitcnt lgkmcnt(0)\ns_barrier" ::: "memory");
  }

  // ---- tile 62 (cur=0): entering queue = [A62(3), B63(1)] ----
  ISSUE_A(63, laB1);
  __builtin_amdgcn_sched_barrier(0);
  asm volatile("s_waitcnt vmcnt(4)" ::: "memory");  // drain A62
  COMPUTE(0);
  __builtin_amdgcn_sched_barrier(0);
  asm volatile("s_waitcnt vmcnt(3)" ::: "memory");  // drain B63
  BCONV(bvA, &Bls[1][0]);
  asm volatile("s_waitcnt lgkmcnt(0)\ns_barrier" ::: "memory");

  // ---- tile 63 (cur=1) ----
  asm volatile("s_waitcnt vmcnt(0)" ::: "memory");  // drain A63(3)
  COMPUTE(1);

#undef ISSUE_A
#undef BCONV
#undef COMPUTE

#pragma unroll
  for (int r = 0; r < 16; r++) {
    const int grow = h * BM + w * 32 + (r & 3) + 8 * (r >> 2) + 4 * lh;
    const float it = s_invT[grow];
    float v0 = (accH[0][r] + accC[0][r] * INV2048F) * it;
    float v1 = (accH[1][r] + accC[1][r] * INV2048F) * it;
    C[(size_t)grow * NV + n0 + l31] = v0;
    C[(size_t)grow * NV + n0 + 32 + l31] = v1;
    float mx = fmaxf(v0, v1);
#pragma unroll
    for (int o = 1; o < 32; o <<= 1) mx = fmaxf(mx, __shfl_xor(mx, o));
    if (l31 == 0) atomicMax(&s_pm[grow], mono_enc(mx));
  }
  __syncthreads();
  atomicMax(&rowmax[t], s_pm[t]);
}

// ---------------- fused per-row sampler, 1024 threads, u32-atomic histograms --------
// (unchanged from R3)
__global__ __launch_bounds__(1024) void sample_row(
    float* __restrict__ buf, const unsigned* __restrict__ rowmax,
    const int* __restrict__ toks, const float* __restrict__ pres,
    const float* __restrict__ freq, const float* __restrict__ temp,
    const float* __restrict__ topp_a, const int* __restrict__ topk_a) {
  extern __shared__ char smem[];
  float* e = (float*)smem;                               // 32000 f32
  unsigned* hist = (unsigned*)(smem + NV * 4);           // HTOT u32
  unsigned long long* suf = (unsigned long long*)hist;   // 1024 u64, aliases lo0|lo1
  __shared__ int s_tok[NT];
  __shared__ int s_bs;
  __shared__ RowP2 sp;

  const int b = blockIdx.x, t = threadIdx.x;
  const int cp = (t >> 6) & 1;
  unsigned* loP = hist + cp * HSTR;
  unsigned* hcP = hist + 2 * HSTR + cp * HSTR;
  float* row = buf + (size_t)b * NV;

#define HACC(EV, BIN)                                                    \
  do {                                                                   \
    unsigned long long f_ = (unsigned long long)((double)(EV) * FIX2);   \
    unsigned flo_ = (unsigned)f_;                                        \
    unsigned old_ = atomicAdd(&loP[BIN], flo_);                          \
    unsigned hc_ = 0x10000u + (unsigned)(f_ >> 32) +                     \
                   ((old_ + flo_ < flo_) ? 1u : 0u);                     \
    atomicAdd(&hcP[BIN], hc_);                                           \
  } while (0)

  // ---- load row into LDS, zero hist ----
  if (t < NT) s_tok[t] = toks[b * NT + t];
  for (int i = t; i < HTOT; i += 1024) hist[i] = 0u;
  for (int i4 = t; i4 < NV / 4; i4 += 1024)
    *(float4*)(e + i4 * 4) = *(const float4*)(row + i4 * 4);
  __syncthreads();

  // ---- penalties ----
  if (t < NT) {
    const int tk = s_tok[t];
    bool first = true; int cnt = 0;
    for (int j = 0; j < NT; j++)
      if (s_tok[j] == tk) { if (j < t) first = false; cnt++; }
    if (first) e[tk] -= (freq[b] * (float)cnt + pres[b]) / temp[b];
  }
  __syncthreads();

  // ---- pass 0: exp in place + level-0 histogram (bin = k>>20) ----
  const float M = mono_dec(rowmax[b]);
  for (int i4 = t; i4 < NV / 4; i4 += 1024) {
    float4 x4 = *(const float4*)(e + i4 * 4);
    float4 e4;
    e4.x = expf(x4.x - M); e4.y = expf(x4.y - M);
    e4.z = expf(x4.z - M); e4.w = expf(x4.w - M);
    *(float4*)(e + i4 * 4) = e4;
    unsigned k;
    k = __float_as_uint(e4.x); if (k) HACC(e4.x, k >> 20);
    k = __float_as_uint(e4.y); if (k) HACC(e4.y, k >> 20);
    k = __float_as_uint(e4.z); if (k) HACC(e4.z, k >> 20);
    k = __float_as_uint(e4.w); if (k) HACC(e4.w, k >> 20);
  }
  __syncthreads();

  // ---- 3-level radix descent ----
  for (int level = 0; level < 3; level++) {
    const unsigned lo0 = hist[t], lo1 = hist[HSTR + t];
    const unsigned hc0 = hist[2 * HSTR + t], hc1 = hist[3 * HSTR + t];
    const unsigned c = (hc0 >> 16) + (hc1 >> 16);
    const unsigned long long sum =
        (((unsigned long long)((hc0 & 0xFFFFu) + (hc1 & 0xFFFFu))) << 32) +
        (unsigned long long)lo0 + (unsigned long long)lo1;
    const unsigned long long v = ((unsigned long long)c << 48) + sum;
    __syncthreads();
    suf[t] = v;
    __syncthreads();
    for (int off = 1; off < NBIN; off <<= 1) {
      unsigned long long add = (t + off < NBIN) ? suf[t + off] : 0ull;
      __syncthreads();
      suf[t] += add;
      __syncthreads();
    }
    const unsigned long long totalP = suf[0];
    if (t == 0) s_bs = NBIN - 1;
    __syncthreads();

    unsigned long long base, toppZ;
    int ktop_;
    if (level == 0) {
      ktop_ = topk_a[b];
      unsigned long long Zfix = totalP & SMASK;
      if (!Zfix) Zfix = 1ull;
      toppZ = (unsigned long long)((double)topp_a[b] * (double)Zfix);
      base = 0ull;
    } else {
      base = sp.basePack; toppZ = sp.toppZfix; ktop_ = sp.ktop;
    }

    {
      const unsigned long long sG = base + suf[t];
      const bool A = ((long long)(sG >> 48) < (long long)ktop_) && ((sG & SMASK) <= toppZ);
      const unsigned long long sP = base + ((t > 0) ? suf[t - 1] : totalP);
      const bool Ap = ((long long)(sP >> 48) < (long long)ktop_) && ((sP & SMASK) <= toppZ);
      if (A && !Ap) s_bs = t;
    }
    __syncthreads();
    if (t == 0) {
      const int bs = s_bs;
      const unsigned long long newBase = base + suf[bs];
      if (level == 0) {
        unsigned long long Zfix = totalP & SMASK;
        if (!Zfix) Zfix = 1ull;
        sp.invZ = (float)(FIX2 / (double)Zfix);
      }
      if (level < 2) {
        sp.basePack = newBase;
        sp.toppZfix = toppZ;
        sp.ktop = ktop_;
        sp.pfx = (level == 0) ? (unsigned)bs : ((sp.pfx << 10) | (unsigned)bs);
      } else {
        const unsigned ustar = (sp.pfx << 10) | (unsigned)bs;
        const unsigned long long raw = ((bs > 0) ? suf[bs - 1] : totalP) - suf[bs];
        const int cEq = (int)(raw >> 48);
        const long long Chi = (long long)(newBase >> 48);
        const unsigned long long Shi = newBase & SMASK;
        long long m = cEq;
        const long long lim = (long long)ktop_ - Chi;
        if (lim < m) m = lim;
        const double tf = (double)__uint_as_float(ustar) * FIX2;
        const double rem = (double)(toppZ - Shi);
        const double Rd = floor(rem / tf) + 1.0;
        if (Rd < (double)m) m = (long long)Rd;
        if (m < 1) m = 1;
        sp.ustar = ustar; sp.m = (int)m; sp.cEq = cEq;
      }
    }
    __syncthreads();

    if (level < 2) {
      for (int i = t; i < HTOT; i += 1024) hist[i] = 0u;
      __syncthreads();
      const unsigned pfx = sp.pfx;
      const int ms = (level == 0) ? 20 : 10;
      const int bsh = (level == 0) ? 10 : 0;
      for (int i4 = t; i4 < NV / 4; i4 += 1024) {
        float4 e4 = *(const float4*)(e + i4 * 4);
        unsigned k;
        k = __float_as_uint(e4.x); if (k && (k >> ms) == pfx) HACC(e4.x, (k >> bsh) & 1023u);
        k = __float_as_uint(e4.y); if (k && (k >> ms) == pfx) HACC(e4.y, (k >> bsh) & 1023u);
        k = __float_as_uint(e4.z); if (k && (k >> ms) == pfx) HACC(e4.z, (k >> bsh) & 1023u);
        k = __float_as_uint(e4.w); if (k && (k >> ms) == pfx) HACC(e4.w, (k >> bsh) & 1023u);
      }
      __syncthreads();
    }
  }
#undef HACC

  // ---- final filter ----
  const unsigned ustar = sp.ustar;
  const float invZ = sp.invZ;
  if (sp.m >= sp.cEq) {
    for (int i4 = t; i4 < NV / 4; i4 += 1024) {
      float4 e4 = *(const float4*)(e + i4 * 4);
      float4 o4;
      unsigned k;
      k = __float_as_uint(e4.x); o4.x = (k >= ustar) ? e4.x * invZ : 0.f;
      k = __float_as_uint(e4.y); o4.y = (k >= ustar) ? e4.y * invZ : 0.f;
      k = __float_as_uint(e4.z); o4.z = (k >= ustar) ? e4.z * invZ : 0.f;
      k = __float_as_uint(e4.w); o4.w = (k >= ustar) ? e4.w * invZ : 0.f;
      *(float4*)(row + i4 * 4) = o4;
    }
  } else {
    const int m = sp.m;
    unsigned* rk = hist;  // 1024 u32, suf dead now
    const int base0 = t * 32;
    const int end0 = (base0 + 32 < NV) ? base0 + 32 : NV;
    int myc = 0;
    for (int v = base0; v < end0; v++)
      myc += (__float_as_uint(e[v]) == ustar);
    rk[t] = (unsigned)myc;
    __syncthreads();
    for (int off = 1; off < 1024; off <<= 1) {
      const unsigned a0 = rk[t];
      const unsigned an = (t >= off) ? rk[t - off] : 0u;
      __syncthreads();
      rk[t] = a0 + an;
      __syncthreads();
    }
    int r = (t > 0) ? (int)rk[t - 1] : 0;
    for (int v = base0; v < end0; v++) {
      const unsigned k = __float_as_uint(e[v]);
      float o = (k > ustar) ? e[v] * invZ : 0.f;
      if (k == ustar) { o = (r < m) ? e[v] * invZ : 0.f; r++; }
      row[v] = o;
    }
  }
}

extern "C" void kernel_launch(void* const* d_in, const int* in_sizes, int n_in,
                              void* d_out, int out_size, void* d_ws, size_t ws_size,
                              hipStream_t stream) {
  (void)in_sizes; (void)n_in; (void)out_size; (void)ws_size;
  const float* hidden = (const float*)d_in[0];
  const float* emb    = (const float*)d_in[1];
  const int*   toks   = (const int*)d_in[2];
  const float* pres   = (const float*)d_in[3];
  const float* freq   = (const float*)d_in[4];
  const float* temp   = (const float*)d_in[5];
  const float* topp   = (const float*)d_in[6];
  const int*   topk   = (const int*)d_in[7];
  float* out = (float*)d_out;

  // ws layout: A3 (64*24576 = 1,572,864 B) + rowmax (1,024 B, zeroed)
  const size_t offA3 = 0;
  const size_t offRM = 1572864;

  _Float16* A3 = (_Float16*)((char*)d_ws + offA3);
  unsigned* rowmax = (unsigned*)((char*)d_ws + offRM);

  hipFuncSetAttribute((const void*)sample_row,
                      hipFuncAttributeMaxDynamicSharedMemorySize, SMEM_BYTES);

  hipMemsetAsync((char*)d_ws + offRM, 0, 1024, stream);
  convert_A<<<256, 256, 0, stream>>>(hidden, A3);
  gemm_f16s<<<1008, 256, 0, stream>>>(emb, A3, temp, rowmax, out);
  sample_row<<<NB, 1024, SMEM_BYTES, stream>>>(out, rowmax, toks, pres, freq,
                                               temp, topp, topk);
}

// Round 7
// 267.355 us; speedup vs baseline: 1.1353x; 1.1353x over previous
//
#include <hip/hip_runtime.h>
#include <math.h>

#define NB 256
#define NV 32000
#define ND 1024
#define NT 64

// ---- GEMM config ----
#define GN 64
#define BSTR 40            // B row stride (f16): [h x16][q x16][pad x8]
#define NKB 64             // 1024/16 k-blocks
#define AKBF 8192          // f16 per k-block, fragment order: 8 strips x 2(h,q) x 64 lanes x 8
#define NGBLK (NV / GN)    // 500
#define INV2048F 4.8828125e-4f

// ---- sampling config ----
#define NBIN 1024
#define HSTR 1032
#define HTOT (4 * HSTR)
#define FIX2 4294967296.0
#define SMASK ((1ull << 48) - 1ull)
#define SMEM_BYTES (NV * 4 + HTOT * 4)  // 144512 B

typedef _Float16 f16x8 __attribute__((ext_vector_type(8)));
typedef _Float16 f16x4 __attribute__((ext_vector_type(4)));
typedef float f32x16 __attribute__((ext_vector_type(16)));

struct RowP2 {
  unsigned long long basePack;
  unsigned long long toppZfix;
  unsigned pfx;
  int ktop;
  float invZ;
  unsigned ustar;
  int m;
  int cEq;
};

__device__ __forceinline__ unsigned mono_enc(float f) {
  unsigned u = __float_as_uint(f);
  return (u & 0x80000000u) ? ~u : (u | 0x80000000u);
}
__device__ __forceinline__ float mono_dec(unsigned u) {
  return (u & 0x80000000u) ? __uint_as_float(u & 0x7FFFFFFFu) : __uint_as_float(~u);
}

// ---------------- convert A: write MFMA-fragment-ordered h/q planes ----------------
// Element A[r][kb*16 + lh*8 + j] (r = strip*32 + l31, lane = l31 + 32*lh) lands at
//   A3[kb*AKBF + ((strip*2 + hq)*64 + lane)*8 + j]
// so a wave's fragment load is 64 lanes x 16B contiguous (perfectly coalesced).
__global__ __launch_bounds__(256) void convert_A(const float* __restrict__ hidden,
                                                 _Float16* __restrict__ A3) {
  const int g = blockIdx.x * 256 + threadIdx.x;   // 65536 total
  const int kb = g >> 10, rem = g & 1023, r = rem >> 2, c = rem & 3;
  const float4 a4 = *(const float4*)(hidden + (size_t)r * ND + kb * 16 + c * 4);
  const float v[4] = {a4.x, a4.y, a4.z, a4.w};
  f16x4 h4, q4;
#pragma unroll
  for (int q = 0; q < 4; q++) {
    const _Float16 hh = (_Float16)v[q];
    h4[q] = hh;
    q4[q] = (_Float16)((v[q] - (float)hh) * 2048.0f);
  }
  const int s = r >> 5, l31 = r & 31;
  const int lh = c >> 1, j4 = (c & 1) * 4;
  const int lane = l31 + (lh << 5);
  _Float16* base = A3 + (size_t)kb * AKBF;
  *(f16x4*)(base + ((s * 2 + 0) * 64 + lane) * 8 + j4) = h4;
  *(f16x4*)(base + ((s * 2 + 1) * 64 + lane) * 8 + j4) = q4;
}

// ---------------- MFMA f16-split GEMM: A in registers, B in LDS dbuf ----------------
// A path: fragment-ordered A3 (1 MB, L2-resident) -> per-wave coalesced 1KB register
// loads, prefetched 2 iterations deep, compiler-managed waits. No A-LDS, no
// global_load_lds, no A share of the barrier chain. B path: unchanged R5 (float4
// prefetch -> BCONV -> ds_write -> lgkmcnt(0)+barrier -> 4 ds_read_b128/wave).
__global__ __launch_bounds__(256, 2) void gemm_f16s(
    const float* __restrict__ Bm, const _Float16* __restrict__ A3,
    const float* __restrict__ temp, unsigned* __restrict__ rowmax,
    float* __restrict__ C) {
  __shared__ _Float16 Bls[2][GN * BSTR];  // 10,240 B
  __shared__ float s_invT[256];
  __shared__ unsigned s_pm[256];

  const int t = threadIdx.x;
  const int l = t & 63, w = t >> 6;
  const int n0 = blockIdx.x * GN;
  s_invT[t] = 1.0f / temp[t];
  s_pm[t] = 0u;

  f32x16 accH[2][2] = {};  // [strip][ncol] h*h'
  f32x16 accC[2][2] = {};  // h*q' + q*h' (scaled by 2048)

  const int bn = t >> 2, bk4 = (t & 3) * 4;
  const int l31 = l & 31, lh = l >> 5;
  const int ka = lh * 8;
  const int mb = w * 64;

  const float* browp = Bm + (size_t)(n0 + bn) * ND + bk4;
  // wave w owns strips 2w (offset 0), 2w+1 (offset 1024 f16); q-planes at +512.
  const _Float16* aB = A3 + 2048 * w + l * 8;

  f16x8 eh0, eh1, eq0, eq1;  // even-iteration A fragments
  f16x8 oh0, oh1, oq0, oq1;  // odd-iteration A fragments

#define LOADA(P, KB)                                                  \
  do {                                                                \
    const _Float16* ap_ = aB + (size_t)(KB) * AKBF;                   \
    P##h0 = *(const f16x8*)(ap_);                                     \
    P##q0 = *(const f16x8*)(ap_ + 512);                               \
    P##h1 = *(const f16x8*)(ap_ + 1024);                              \
    P##q1 = *(const f16x8*)(ap_ + 1536);                              \
  } while (0)

#define BCONV(BV, DST)                                                \
  do {                                                                \
    f16x4 h4_, q4_;                                                   \
    const float vv_[4] = {(BV).x, (BV).y, (BV).z, (BV).w};            \
    _Pragma("unroll") for (int j_ = 0; j_ < 4; j_++) {                \
      const _Float16 h_ = (_Float16)vv_[j_];                          \
      h4_[j_] = h_;                                                   \
      q4_[j_] = (_Float16)((vv_[j_] - (float)h_) * 2048.0f);          \
    }                                                                 \
    _Float16* prow_ = (DST) + bn * BSTR;                              \
    *(f16x4*)(prow_ + bk4) = h4_;                                     \
    *(f16x4*)(prow_ + 16 + bk4) = q4_;                                \
  } while (0)

#define COMPUTE(P, CUR)                                                                     \
  do {                                                                                      \
    const _Float16* Bp_ = &Bls[CUR][0] + (size_t)l31 * BSTR + ka;                           \
    f16x8 b0h_ = *(const f16x8*)(Bp_);                                                      \
    f16x8 b1h_ = *(const f16x8*)(Bp_ + 32 * BSTR);                                          \
    accH[0][0] = __builtin_amdgcn_mfma_f32_32x32x16_f16(P##h0, b0h_, accH[0][0], 0, 0, 0);  \
    accH[0][1] = __builtin_amdgcn_mfma_f32_32x32x16_f16(P##h0, b1h_, accH[0][1], 0, 0, 0);  \
    accH[1][0] = __builtin_amdgcn_mfma_f32_32x32x16_f16(P##h1, b0h_, accH[1][0], 0, 0, 0);  \
    accH[1][1] = __builtin_amdgcn_mfma_f32_32x32x16_f16(P##h1, b1h_, accH[1][1], 0, 0, 0);  \
    f16x8 b0q_ = *(const f16x8*)(Bp_ + 16);                                                 \
    f16x8 b1q_ = *(const f16x8*)(Bp_ + 32 * BSTR + 16);                                     \
    accC[0][0] = __builtin_amdgcn_mfma_f32_32x32x16_f16(P##h0, b0q_, accC[0][0], 0, 0, 0);  \
    accC[0][1] = __builtin_amdgcn_mfma_f32_32x32x16_f16(P##h0, b1q_, accC[0][1], 0, 0, 0);  \
    accC[1][0] = __builtin_amdgcn_mfma_f32_32x32x16_f16(P##h1, b0q_, accC[1][0], 0, 0, 0);  \
    accC[1][1] = __builtin_amdgcn_mfma_f32_32x32x16_f16(P##h1, b1q_, accC[1][1], 0, 0, 0);  \
    accC[0][0] = __builtin_amdgcn_mfma_f32_32x32x16_f16(P##q0, b0h_, accC[0][0], 0, 0, 0);  \
    accC[0][1] = __builtin_amdgcn_mfma_f32_32x32x16_f16(P##q0, b1h_, accC[0][1], 0, 0, 0);  \
    accC[1][0] = __builtin_amdgcn_mfma_f32_32x32x16_f16(P##q1, b0h_, accC[1][0], 0, 0, 0);  \
    accC[1][1] = __builtin_amdgcn_mfma_f32_32x32x16_f16(P##q1, b1h_, accC[1][1], 0, 0, 0);  \
  } while (0)

  // ---- prologue: A(0)->e, A(1)->o, B(0) built, f4(1) in flight ----
  LOADA(e, 0);
  __builtin_amdgcn_sched_barrier(0);
  float4 bv0 = *(const float4*)(browp);
  __builtin_amdgcn_sched_barrier(0);
  LOADA(o, 1);
  __builtin_amdgcn_sched_barrier(0);
  float4 bvA = *(const float4*)(browp + 16);  // f4(1)
  __builtin_amdgcn_sched_barrier(0);
  BCONV(bv0, &Bls[0][0]);
  asm volatile("s_waitcnt lgkmcnt(0)\ns_barrier" ::: "memory");

  float4 bvB;
  // invariant entering pair kb: e=A(kb), o=A(kb+1), Bls[0]=B(kb), bvA=f4(kb+1)
  for (int kb = 0; kb < 62; kb += 2) {
    COMPUTE(e, 0);
    __builtin_amdgcn_sched_barrier(0);
    LOADA(e, kb + 2);
    __builtin_amdgcn_sched_barrier(0);
    bvB = *(const float4*)(browp + (size_t)(kb + 2) * 16);
    __builtin_amdgcn_sched_barrier(0);
    BCONV(bvA, &Bls[1][0]);
    asm volatile("s_waitcnt lgkmcnt(0)\ns_barrier" ::: "memory");

    COMPUTE(o, 1);
    __builtin_amdgcn_sched_barrier(0);
    LOADA(o, kb + 3);
    __builtin_amdgcn_sched_barrier(0);
    bvA = *(const float4*)(browp + (size_t)(kb + 3) * 16);
    __builtin_amdgcn_sched_barrier(0);
    BCONV(bvB, &Bls[0][0]);
    asm volatile("s_waitcnt lgkmcnt(0)\ns_barrier" ::: "memory");
  }
  // tail: e=A(62), o=A(63), Bls[0]=B(62), bvA=f4(63)
  COMPUTE(e, 0);
  __builtin_amdgcn_sched_barrier(0);
  BCONV(bvA, &Bls[1][0]);
  asm volatile("s_waitcnt lgkmcnt(0)\ns_barrier" ::: "memory");
  COMPUTE(o, 1);

#undef LOADA
#undef BCONV
#undef COMPUTE

#pragma unroll
  for (int mi = 0; mi < 2; mi++) {
#pragma unroll
    for (int r = 0; r < 16; r++) {
      const int row = mb + mi * 32 + (r & 3) + 8 * (r >> 2) + 4 * lh;
      const float it = s_invT[row];
      float v0 = (accH[mi][0][r] + accC[mi][0][r] * INV2048F) * it;
      float v1 = (accH[mi][1][r] + accC[mi][1][r] * INV2048F) * it;
      C[(size_t)row * NV + n0 + l31] = v0;
      C[(size_t)row * NV + n0 + 32 + l31] = v1;
      float mx = fmaxf(v0, v1);
#pragma unroll
      for (int o = 1; o < 32; o <<= 1) mx = fmaxf(mx, __shfl_xor(mx, o));
      if (l31 == 0) atomicMax(&s_pm[row], mono_enc(mx));
    }
  }
  __syncthreads();
  atomicMax(&rowmax[t], s_pm[t]);
}

// ---------------- fused per-row sampler, 1024 threads, u32-atomic histograms --------
// (unchanged)
__global__ __launch_bounds__(1024) void sample_row(
    float* __restrict__ buf, const unsigned* __restrict__ rowmax,
    const int* __restrict__ toks, const float* __restrict__ pres,
    const float* __restrict__ freq, const float* __restrict__ temp,
    const float* __restrict__ topp_a, const int* __restrict__ topk_a) {
  extern __shared__ char smem[];
  float* e = (float*)smem;
  unsigned* hist = (unsigned*)(smem + NV * 4);
  unsigned long long* suf = (unsigned long long*)hist;
  __shared__ int s_tok[NT];
  __shared__ int s_bs;
  __shared__ RowP2 sp;

  const int b = blockIdx.x, t = threadIdx.x;
  const int cp = (t >> 6) & 1;
  unsigned* loP = hist + cp * HSTR;
  unsigned* hcP = hist + 2 * HSTR + cp * HSTR;
  float* row = buf + (size_t)b * NV;

#define HACC(EV, BIN)                                                    \
  do {                                                                   \
    unsigned long long f_ = (unsigned long long)((double)(EV) * FIX2);   \
    unsigned flo_ = (unsigned)f_;                                        \
    unsigned old_ = atomicAdd(&loP[BIN], flo_);                          \
    unsigned hc_ = 0x10000u + (unsigned)(f_ >> 32) +                     \
                   ((old_ + flo_ < flo_) ? 1u : 0u);                     \
    atomicAdd(&hcP[BIN], hc_);                                           \
  } while (0)

  if (t < NT) s_tok[t] = toks[b * NT + t];
  for (int i = t; i < HTOT; i += 1024) hist[i] = 0u;
  for (int i4 = t; i4 < NV / 4; i4 += 1024)
    *(float4*)(e + i4 * 4) = *(const float4*)(row + i4 * 4);
  __syncthreads();

  if (t < NT) {
    const int tk = s_tok[t];
    bool first = true; int cnt = 0;
    for (int j = 0; j < NT; j++)
      if (s_tok[j] == tk) { if (j < t) first = false; cnt++; }
    if (first) e[tk] -= (freq[b] * (float)cnt + pres[b]) / temp[b];
  }
  __syncthreads();

  const float M = mono_dec(rowmax[b]);
  for (int i4 = t; i4 < NV / 4; i4 += 1024) {
    float4 x4 = *(const float4*)(e + i4 * 4);
    float4 e4;
    e4.x = expf(x4.x - M); e4.y = expf(x4.y - M);
    e4.z = expf(x4.z - M); e4.w = expf(x4.w - M);
    *(float4*)(e + i4 * 4) = e4;
    unsigned k;
    k = __float_as_uint(e4.x); if (k) HACC(e4.x, k >> 20);
    k = __float_as_uint(e4.y); if (k) HACC(e4.y, k >> 20);
    k = __float_as_uint(e4.z); if (k) HACC(e4.z, k >> 20);
    k = __float_as_uint(e4.w); if (k) HACC(e4.w, k >> 20);
  }
  __syncthreads();

  for (int level = 0; level < 3; level++) {
    const unsigned lo0 = hist[t], lo1 = hist[HSTR + t];
    const unsigned hc0 = hist[2 * HSTR + t], hc1 = hist[3 * HSTR + t];
    const unsigned c = (hc0 >> 16) + (hc1 >> 16);
    const unsigned long long sum =
        (((unsigned long long)((hc0 & 0xFFFFu) + (hc1 & 0xFFFFu))) << 32) +
        (unsigned long long)lo0 + (unsigned long long)lo1;
    const unsigned long long v = ((unsigned long long)c << 48) + sum;
    __syncthreads();
    suf[t] = v;
    __syncthreads();
    for (int off = 1; off < NBIN; off <<= 1) {
      unsigned long long add = (t + off < NBIN) ? suf[t + off] : 0ull;
      __syncthreads();
      suf[t] += add;
      __syncthreads();
    }
    const unsigned long long totalP = suf[0];
    if (t == 0) s_bs = NBIN - 1;
    __syncthreads();

    unsigned long long base, toppZ;
    int ktop_;
    if (level == 0) {
      ktop_ = topk_a[b];
      unsigned long long Zfix = totalP & SMASK;
      if (!Zfix) Zfix = 1ull;
      toppZ = (unsigned long long)((double)topp_a[b] * (double)Zfix);
      base = 0ull;
    } else {
      base = sp.basePack; toppZ = sp.toppZfix; ktop_ = sp.ktop;
    }

    {
      const unsigned long long sG = base + suf[t];
      const bool A = ((long long)(sG >> 48) < (long long)ktop_) && ((sG & SMASK) <= toppZ);
      const unsigned long long sP = base + ((t > 0) ? suf[t - 1] : totalP);
      const bool Ap = ((long long)(sP >> 48) < (long long)ktop_) && ((sP & SMASK) <= toppZ);
      if (A && !Ap) s_bs = t;
    }
    __syncthreads();
    if (t == 0) {
      const int bs = s_bs;
      const unsigned long long newBase = base + suf[bs];
      if (level == 0) {
        unsigned long long Zfix = totalP & SMASK;
        if (!Zfix) Zfix = 1ull;
        sp.invZ = (float)(FIX2 / (double)Zfix);
      }
      if (level < 2) {
        sp.basePack = newBase;
        sp.toppZfix = toppZ;
        sp.ktop = ktop_;
        sp.pfx = (level == 0) ? (unsigned)bs : ((sp.pfx << 10) | (unsigned)bs);
      } else {
        const unsigned ustar = (sp.pfx << 10) | (unsigned)bs;
        const unsigned long long raw = ((bs > 0) ? suf[bs - 1] : totalP) - suf[bs];
        const int cEq = (int)(raw >> 48);
        const long long Chi = (long long)(newBase >> 48);
        const unsigned long long Shi = newBase & SMASK;
        long long m = cEq;
        const long long lim = (long long)ktop_ - Chi;
        if (lim < m) m = lim;
        const double tf = (double)__uint_as_float(ustar) * FIX2;
        const double rem = (double)(toppZ - Shi);
        const double Rd = floor(rem / tf) + 1.0;
        if (Rd < (double)m) m = (long long)Rd;
        if (m < 1) m = 1;
        sp.ustar = ustar; sp.m = (int)m; sp.cEq = cEq;
      }
    }
    __syncthreads();

    if (level < 2) {
      for (int i = t; i < HTOT; i += 1024) hist[i] = 0u;
      __syncthreads();
      const unsigned pfx = sp.pfx;
      const int ms = (level == 0) ? 20 : 10;
      const int bsh = (level == 0) ? 10 : 0;
      for (int i4 = t; i4 < NV / 4; i4 += 1024) {
        float4 e4 = *(const float4*)(e + i4 * 4);
        unsigned k;
        k = __float_as_uint(e4.x); if (k && (k >> ms) == pfx) HACC(e4.x, (k >> bsh) & 1023u);
        k = __float_as_uint(e4.y); if (k && (k >> ms) == pfx) HACC(e4.y, (k >> bsh) & 1023u);
        k = __float_as_uint(e4.z); if (k && (k >> ms) == pfx) HACC(e4.z, (k >> bsh) & 1023u);
        k = __float_as_uint(e4.w); if (k && (k >> ms) == pfx) HACC(e4.w, (k >> bsh) & 1023u);
      }
      __syncthreads();
    }
  }
#undef HACC

  const unsigned ustar = sp.ustar;
  const float invZ = sp.invZ;
  if (sp.m >= sp.cEq) {
    for (int i4 = t; i4 < NV / 4; i4 += 1024) {
      float4 e4 = *(const float4*)(e + i4 * 4);
      float4 o4;
      unsigned k;
      k = __float_as_uint(e4.x); o4.x = (k >= ustar) ? e4.x * invZ : 0.f;
      k = __float_as_uint(e4.y); o4.y = (k >= ustar) ? e4.y * invZ : 0.f;
      k = __float_as_uint(e4.z); o4.z = (k >= ustar) ? e4.z * invZ : 0.f;
      k = __float_as_uint(e4.w); o4.w = (k >= ustar) ? e4.w * invZ : 0.f;
      *(float4*)(row + i4 * 4) = o4;
    }
  } else {
    const int m = sp.m;
    unsigned* rk = hist;
    const int base0 = t * 32;
    const int end0 = (base0 + 32 < NV) ? base0 + 32 : NV;
    int myc = 0;
    for (int v = base0; v < end0; v++)
      myc += (__float_as_uint(e[v]) == ustar);
    rk[t] = (unsigned)myc;
    __syncthreads();
    for (int off = 1; off < 1024; off <<= 1) {
      const unsigned a0 = rk[t];
      const unsigned an = (t >= off) ? rk[t - off] : 0u;
      __syncthreads();
      rk[t] = a0 + an;
      __syncthreads();
    }
    int r = (t > 0) ? (int)rk[t - 1] : 0;
    for (int v = base0; v < end0; v++) {
      const unsigned k = __float_as_uint(e[v]);
      float o = (k > ustar) ? e[v] * invZ : 0.f;
      if (k == ustar) { o = (r < m) ? e[v] * invZ : 0.f; r++; }
      row[v] = o;
    }
  }
}

extern "C" void kernel_launch(void* const* d_in, const int* in_sizes, int n_in,
                              void* d_out, int out_size, void* d_ws, size_t ws_size,
                              hipStream_t stream) {
  (void)in_sizes; (void)n_in; (void)out_size; (void)ws_size;
  const float* hidden = (const float*)d_in[0];
  const float* emb    = (const float*)d_in[1];
  const int*   toks   = (const int*)d_in[2];
  const float* pres   = (const float*)d_in[3];
  const float* freq   = (const float*)d_in[4];
  const float* temp   = (const float*)d_in[5];
  const float* topp   = (const float*)d_in[6];
  const int*   topk   = (const int*)d_in[7];
  float* out = (float*)d_out;

  // ws layout: A3 (64*16384 = 1,048,576 B) + rowmax (1,024 B, zeroed)
  const size_t offA3 = 0;
  const size_t offRM = 1048576;

  _Float16* A3 = (_Float16*)((char*)d_ws + offA3);
  unsigned* rowmax = (unsigned*)((char*)d_ws + offRM);

  hipFuncSetAttribute((const void*)sample_row,
                      hipFuncAttributeMaxDynamicSharedMemorySize, SMEM_BYTES);

  hipMemsetAsync((char*)d_ws + offRM, 0, 1024, stream);
  convert_A<<<256, 256, 0, stream>>>(hidden, A3);
  gemm_f16s<<<NGBLK, 256, 0, stream>>>(emb, A3, temp, rowmax, out);
  sample_row<<<NB, 1024, SMEM_BYTES, stream>>>(out, rowmax, toks, pres, freq,
                                               temp, topp, topk);
}